// Round 19
// baseline (184.509 us; speedup 1.0000x reference)
//
#include <hip/hip_runtime.h>
#include <hip/hip_cooperative_groups.h>
#include <math.h>

namespace cg = cooperative_groups;

// ---- problem constants (fixed by reference setup) ----
constexpr int Bc    = 4;
constexpr int Nc    = 1024;
constexpr int SEQc  = 512;
constexpr int FOURc = 257;              // rfft output length
constexpr int NROWS = Bc * Nc;          // 4096 (b,n) rows
constexpr int NSMALL = 1024;            // nodes touched by real edges
constexpr int F1c   = 30;               // H1*C1
constexpr int PADH  = 32;               // h1s padded stride (float4-aligned)
constexpr int CAP   = 128;              // max in-degree bucket capacity
constexpr int XPAD  = 258;              // xf row stride (pad for 16B alignment)
constexpr float NEG_SLOPE = 0.2f;

#define DEVFN static __device__ __forceinline__

// ------- K_xf: double-folded Chebyshev cos-transform -> xf buffer -----------
__global__ __launch_bounds__(256) void k_xf(
    const float* __restrict__ occ, const float* __restrict__ prc,
    float* __restrict__ xf, int* __restrict__ cnt) {
  __shared__ float4 z[2][128];            // [row][t]: zp_o, zp_p, zm_o, zm_p
  __shared__ float sp[2][6];              // y0_o,y0_p, y128_o,y128_p, x256_o,x256_p
  const int tid  = threadIdx.x;
  const int lane = tid & 63;
  const int wid  = tid >> 6;
  const int jrow = wid >> 1;              // local row 0..1
  const int half = wid & 1;               // column half 0..1
  const int row  = blockIdx.x * 2 + jrow;

  if (blockIdx.x == 0) {                  // zero bucket counters for the scatter
#pragma unroll
    for (int j = 0; j < 4; ++j) cnt[tid + 256 * j] = 0;
  }

  // staging: tid -> (row j = tid>>7, t = tid&127)
  {
    const int j = tid >> 7;
    const int t = tid & 127;
    const float* ro = occ + (size_t)(blockIdx.x * 2 + j) * SEQc;
    const float* rp = prc + (size_t)(blockIdx.x * 2 + j) * SEQc;
    if (t == 0) {
      sp[j][0] = ro[0];                 sp[j][1] = rp[0];
      sp[j][2] = ro[128] + ro[384];     sp[j][3] = rp[128] + rp[384];
      sp[j][4] = ro[256];               sp[j][5] = rp[256];
    } else {
      float ao = ro[t] + ro[SEQc - t];          // y[t]
      float bo = ro[256 - t] + ro[256 + t];     // y[256-t]
      float ap = rp[t] + rp[SEQc - t];
      float bp = rp[256 - t] + rp[256 + t];
      z[j][t] = make_float4(ao + bo, ap + bp, ao - bo, ap - bp);
    }
  }
  __syncthreads();

  // seeds for cols k0 (even), k0+1 (odd)
  const int k0 = half * 128 + 2 * lane;
  const float a = 6.283185307179586f / 512.0f;  // = pi/256
  float ce = cosf((float)k0 * a),       cpe = 1.f, m2e = 2.f * ce;
  float co = cosf((float)(k0 + 1) * a), cpo = 1.f, m2o = 2.f * co;
  float aeo = 0.f, aep = 0.f, aoo = 0.f, aop = 0.f;

#pragma unroll 4
  for (int t = 1; t < 128; ++t) {
    float4 zv = z[jrow][t];
    aeo = fmaf(zv.x, ce, aeo);
    aep = fmaf(zv.y, ce, aep);
    aoo = fmaf(zv.z, co, aoo);
    aop = fmaf(zv.w, co, aop);
    float ne = fmaf(m2e, ce, -cpe); cpe = ce; ce = ne;
    float no = fmaf(m2o, co, -cpo); cpo = co; co = no;
  }

  const float y0o = sp[jrow][0], y0p = sp[jrow][1];
  const float y128o = sp[jrow][2], y128p = sp[jrow][3];
  const float x256o = sp[jrow][4], x256p = sp[jrow][5];
  const float s128 = (lane & 1) ? -1.f : 1.f;   // (-1)^(k0/2)

  float4 st;                              // {Xe_o, Xe_p, Xo_o, Xo_p}
  st.x = aeo + y0o + s128 * y128o + x256o;
  st.y = aep + y0p + s128 * y128p + x256p;
  st.z = aoo + y0o - x256o;
  st.w = aop + y0p - x256p;
  *reinterpret_cast<float4*>(xf + ((size_t)row * XPAD + k0) * 2) = st;

  // k = 256 column: X256 = y0 + y128 + sum_{t=1}^{127} (-1)^t zp[t] + x256
  if (half == 0) {
    float sgn = (lane & 1) ? -1.f : 1.f;
    float4 zhi = z[jrow][lane + 64];
    float so = sgn * zhi.x, spp = sgn * zhi.y;
    if (lane >= 1) {
      float4 zlo = z[jrow][lane];
      so  = fmaf(sgn, zlo.x, so);
      spp = fmaf(sgn, zlo.y, spp);
    }
#pragma unroll
    for (int off = 32; off; off >>= 1) {
      so  += __shfl_xor(so, off);
      spp += __shfl_xor(spp, off);
    }
    if (lane == 0) {
      float2 st2;
      st2.x = y0o + y128o + so + x256o;
      st2.y = y0p + y128p + spp + x256p;
      *reinterpret_cast<float2*>(xf + ((size_t)row * XPAD + 256) * 2) = st2;
    }
  }
}

// self-loop-only node value: v = elu(xf@W1 + b1) @ W2 + b2
DEVFN float node_v(float xo, float xp,
                   const float* w1s, const float* b1s, const float* w2s, float b2v) {
  float s = 0.f;
#pragma unroll
  for (int jj = 0; jj < F1c; ++jj) {
    float h = fmaf(xo, w1s[jj], fmaf(xp, w1s[F1c + jj], b1s[jj]));
    float e = h > 0.f ? h : (__expf(h) - 1.f);
    s = fmaf(e, w2s[jj], s);
  }
  return s + b2v;
}

// layer-1 prep for small-graph nodes (padded strides: h1s 32, a1s/a1d 4)
DEVFN void small_prep(int node, float xo, float xp,
                      const float* w1s, const float* s1, const float* d1,
                      float* h1s, float* a1s, float* a1d) {
#pragma unroll
  for (int h = 0; h < 3; ++h) {
    float as = 0.f, ad = 0.f;
#pragma unroll
    for (int c = 0; c < 10; ++c) {
      int jj = h * 10 + c;
      float hv = fmaf(xo, w1s[jj], xp * w1s[F1c + jj]);
      h1s[node * PADH + jj] = hv;
      as = fmaf(hv, s1[jj], as);
      ad = fmaf(hv, d1[jj], ad);
    }
    a1s[node * 4 + h] = as;
    a1d[node * 4 + h] = ad;
  }
}

// ---- shared device bodies (used by both coop phases and fallback kernels) ----
DEVFN void post_row(int row, int tid, int lane, int wid,
                    const float* xf, const float* w1s, const float* b1s,
                    const float* w2s, const float* s1, const float* d1,
                    float b2v, const float* decW, const float* decb,
                    float* out, float* vsm, float* h1s, float* a1s, float* a1d,
                    float* red) {
  const bool smallrow = (row < 4);
  float2 v2 = *reinterpret_cast<const float2*>(xf + ((size_t)row * XPAD + tid) * 2);
  float vv = node_v(v2.x, v2.y, w1s, b1s, w2s, b2v);
  float s = vv * decW[tid];
  if (tid == 0) {                         // col 256
    float2 v6 = *reinterpret_cast<const float2*>(xf + ((size_t)row * XPAD + 256) * 2);
    float v256 = node_v(v6.x, v6.y, w1s, b1s, w2s, b2v);
    s = fmaf(v256, decW[256], s);
    if (smallrow) {
      int node = row * FOURc + 256;
      if (node < NSMALL) {
        vsm[node] = v256;
        small_prep(node, v6.x, v6.y, w1s, s1, d1, h1s, a1s, a1d);
      }
    }
  }
  if (smallrow) {
    int node = row * FOURc + tid;
    if (node < NSMALL) {
      vsm[node] = vv;
      small_prep(node, v2.x, v2.y, w1s, s1, d1, h1s, a1s, a1d);
    }
  }
#pragma unroll
  for (int off = 32; off; off >>= 1) s += __shfl_xor(s, off);
  if (lane == 0) red[wid] = s;
  __syncthreads();
  if (tid == 0) out[row] = red[0] + red[1] + red[2] + red[3] + decb[0];
  __syncthreads();
}

DEVFN void scatter_chunk(int chunk, int tid, const int* ei, int E,
                         int* cnt, int* srcs2) {
  const int base = chunk * 256 + tid;
  const int tot  = E + NSMALL;
  for (int e = base; e < tot; e += 32 * 256) {
    int src, dst;
    if (e < E) { src = ei[e]; dst = ei[E + e]; }
    else       { src = dst = e - E; }     // self loops
    int pos = atomicAdd(&cnt[dst], 1);
    if (pos < CAP) srcs2[dst * CAP + pos] = src;
  }
}

DEVFN void g1_dst(int dst, int lane,
                  const int* cnt, const int* srcs2,
                  const float* a1s, const float* a1d, const float* h1s,
                  const float* b1s, const float* w2s,
                  const float* as2, const float* ad2,
                  float* h2s, float* a2s, float* a2d) {
  const int deg = cnt[dst];
  const int* sp = srcs2 + dst * CAP;
  const float ad0 = a1d[dst * 4], ad1v = a1d[dst * 4 + 1], ad2v = a1d[dst * 4 + 2];
  float den[3] = {0.f, 0.f, 0.f};
  float num[F1c];
#pragma unroll
  for (int j = 0; j < F1c; ++j) num[j] = 0.f;

  for (int p = lane; p < deg; p += 64) {
    int src = sp[p];
    const float4* hs4 = reinterpret_cast<const float4*>(h1s + src * PADH);
    float4 av = *reinterpret_cast<const float4*>(a1s + src * 4);
    float x0 = av.x + ad0;
    float x1 = av.y + ad1v;
    float x2 = av.z + ad2v;
    x0 = x0 > 0.f ? x0 : NEG_SLOPE * x0;
    x1 = x1 > 0.f ? x1 : NEG_SLOPE * x1;
    x2 = x2 > 0.f ? x2 : NEG_SLOPE * x2;
    float ev[3] = {__expf(x0), __expf(x1), __expf(x2)};
    den[0] += ev[0]; den[1] += ev[1]; den[2] += ev[2];
#pragma unroll
    for (int m = 0; m < 7; ++m) {
      float4 hv = hs4[m];
      num[4 * m + 0] = fmaf(ev[(4 * m + 0) / 10], hv.x, num[4 * m + 0]);
      num[4 * m + 1] = fmaf(ev[(4 * m + 1) / 10], hv.y, num[4 * m + 1]);
      num[4 * m + 2] = fmaf(ev[(4 * m + 2) / 10], hv.z, num[4 * m + 2]);
      num[4 * m + 3] = fmaf(ev[(4 * m + 3) / 10], hv.w, num[4 * m + 3]);
    }
    float2 h7 = *reinterpret_cast<const float2*>(h1s + src * PADH + 28);
    num[28] = fmaf(ev[2], h7.x, num[28]);
    num[29] = fmaf(ev[2], h7.y, num[29]);
  }
#pragma unroll
  for (int h = 0; h < 3; ++h)
#pragma unroll
    for (int off = 32; off; off >>= 1) den[h] += __shfl_xor(den[h], off);
#pragma unroll
  for (int j = 0; j < F1c; ++j)
#pragma unroll
    for (int off = 32; off; off >>= 1) num[j] += __shfl_xor(num[j], off);

  if (lane == 0) {
    float h2 = 0.f;
#pragma unroll
    for (int jj = 0; jj < F1c; ++jj) {
      float x2 = num[jj] / den[jj / 10] + b1s[jj];
      x2 = x2 > 0.f ? x2 : (__expf(x2) - 1.f);
      h2 = fmaf(x2, w2s[jj], h2);
    }
    h2s[dst] = h2;
    a2s[dst] = h2 * as2[0];
    a2d[dst] = h2 * ad2[0];
  }
}

DEVFN void g2_dst(int dst, int tid, int lane, int wid,
                  const int* cnt, const int* srcs2,
                  const float* a2s, const float* a2d, const float* h2s,
                  float b2v, const float* vsm, const float* decW,
                  float* out, float* rcor, int* rrow) {
  const int deg = cnt[dst];
  const int* sp = srcs2 + dst * CAP;
  const float adv = a2d[dst];
  float den = 0.f, num = 0.f;
  for (int p = lane; p < deg; p += 64) {
    int src = sp[p];
    float x = a2s[src] + adv;
    x = x > 0.f ? x : NEG_SLOPE * x;
    float ex = __expf(x);
    den += ex;
    num = fmaf(ex, h2s[src], num);
  }
#pragma unroll
  for (int off = 32; off; off >>= 1) {
    den += __shfl_xor(den, off);
    num += __shfl_xor(num, off);
  }
  if (lane == 0) {
    float val2v = num / den + b2v;
    int r = dst / FOURc;
    int k = dst - r * FOURc;
    rcor[wid] = (val2v - vsm[dst]) * decW[k];
    rrow[wid] = r;
  }
  __syncthreads();
  if (tid == 0) {
    float acc = rcor[0];
#pragma unroll
    for (int i = 1; i < 4; ++i) {
      if (rrow[i] == rrow[0]) acc += rcor[i];
      else atomicAdd(&out[rrow[i]], rcor[i]);
    }
    atomicAdd(&out[rrow[0]], acc);
  }
}

// ------- K_coop: {post+scatter} -> grid.sync -> g1 -> grid.sync -> g2 -------
// 512 blocks (needs only 2 blocks/CU co-residency; r18's 1024 was at the
// exact capacity edge and the launch errored -> out never written).
__global__ __launch_bounds__(256, 4) void k_coop(
    const float* __restrict__ xf,
    const float* __restrict__ W1, const float* __restrict__ b1,
    const float* __restrict__ W2, const float* __restrict__ b2,
    const float* __restrict__ as1, const float* __restrict__ ad1,
    const float* __restrict__ as2, const float* __restrict__ ad2,
    const float* __restrict__ decW, const float* __restrict__ decb,
    const int* __restrict__ ei, int E,
    float* __restrict__ out, float* __restrict__ vsm,
    float* __restrict__ h1s, float* __restrict__ a1s, float* __restrict__ a1d,
    float* __restrict__ h2s, float* __restrict__ a2s, float* __restrict__ a2d,
    int* __restrict__ cnt, int* __restrict__ srcs2) {
  cg::grid_group grid = cg::this_grid();
  const int tid  = threadIdx.x;
  const int lane = tid & 63;
  const int wid  = tid >> 6;
  const int nb   = gridDim.x;

  __shared__ float wl[192];
  __shared__ float red[4];
  __shared__ float rcor[4];
  __shared__ int   rrow[4];

  if      (tid < 60)  wl[tid] = W1[tid];
  else if (tid < 90)  wl[tid] = b1[tid - 60];
  else if (tid < 120) wl[tid] = W2[tid - 90];
  else if (tid < 150) wl[tid] = as1[tid - 120];
  else if (tid < 180) wl[tid] = ad1[tid - 150];
  __syncthreads();
  const float* w1s = wl;
  const float* b1s = wl + 60;
  const float* w2s = wl + 90;
  const float* s1  = wl + 120;
  const float* d1  = wl + 150;
  const float b2v  = b2[0];

  for (int u = blockIdx.x; u < NROWS + 32; u += nb) {
    if (u < NROWS)
      post_row(u, tid, lane, wid, xf, w1s, b1s, w2s, s1, d1, b2v,
               decW, decb, out, vsm, h1s, a1s, a1d, red);
    else
      scatter_chunk(u - NROWS, tid, ei, E, cnt, srcs2);
  }
  grid.sync();

  for (int u = blockIdx.x; u < NSMALL / 4; u += nb)
    g1_dst(u * 4 + wid, lane, cnt, srcs2, a1s, a1d, h1s,
           b1s, w2s, as2, ad2, h2s, a2s, a2d);
  grid.sync();

  for (int u = blockIdx.x; u < NSMALL / 4; u += nb)
    g2_dst(u * 4 + wid, tid, lane, wid, cnt, srcs2, a2s, a2d, h2s,
           b2v, vsm, decW, out, rcor, rrow);
}

// ------- fallback kernels (r17-proven path, engaged if coop launch errors) ---
__global__ __launch_bounds__(256) void k_post(
    const float* __restrict__ xf,
    const float* __restrict__ W1, const float* __restrict__ b1,
    const float* __restrict__ W2, const float* __restrict__ b2,
    const float* __restrict__ as1, const float* __restrict__ ad1,
    const float* __restrict__ decW, const float* __restrict__ decb,
    float* __restrict__ out, float* __restrict__ vsm,
    float* __restrict__ h1s, float* __restrict__ a1s, float* __restrict__ a1d,
    const int* __restrict__ ei, int E,
    int* __restrict__ cnt, int* __restrict__ srcs2) {
  const int tid = threadIdx.x;
  if (blockIdx.x >= NROWS) {
    scatter_chunk(blockIdx.x - NROWS, tid, ei, E, cnt, srcs2);
    return;
  }
  __shared__ float wl[192];
  __shared__ float red[4];
  if      (tid < 60)  wl[tid] = W1[tid];
  else if (tid < 90)  wl[tid] = b1[tid - 60];
  else if (tid < 120) wl[tid] = W2[tid - 90];
  else if (tid < 150) wl[tid] = as1[tid - 120];
  else if (tid < 180) wl[tid] = ad1[tid - 150];
  __syncthreads();
  post_row(blockIdx.x, tid, tid & 63, tid >> 6, xf, wl, wl + 60, wl + 90,
           wl + 120, wl + 150, b2[0], decW, decb, out, vsm, h1s, a1s, a1d, red);
}

__global__ __launch_bounds__(256) void k_g1(
    const int* __restrict__ cnt, const int* __restrict__ srcs2,
    const float* __restrict__ a1s, const float* __restrict__ a1d,
    const float* __restrict__ h1s,
    const float* __restrict__ b1, const float* __restrict__ W2,
    const float* __restrict__ as2, const float* __restrict__ ad2,
    float* __restrict__ h2s, float* __restrict__ a2s, float* __restrict__ a2d) {
  g1_dst(blockIdx.x * 4 + (threadIdx.x >> 6), threadIdx.x & 63,
         cnt, srcs2, a1s, a1d, h1s, b1, W2, as2, ad2, h2s, a2s, a2d);
}

__global__ __launch_bounds__(256) void k_g2(
    const int* __restrict__ cnt, const int* __restrict__ srcs2,
    const float* __restrict__ a2s, const float* __restrict__ a2d,
    const float* __restrict__ h2s, const float* __restrict__ b2,
    const float* __restrict__ vsm, const float* __restrict__ decW,
    float* __restrict__ out) {
  __shared__ float rcor[4];
  __shared__ int   rrow[4];
  g2_dst(blockIdx.x * 4 + (threadIdx.x >> 6), threadIdx.x, threadIdx.x & 63,
         threadIdx.x >> 6, cnt, srcs2, a2s, a2d, h2s, b2[0], vsm, decW,
         out, rcor, rrow);
}

// ---------------- host launcher ----------------
extern "C" void kernel_launch(void* const* d_in, const int* in_sizes, int n_in,
                              void* d_out, int out_size, void* d_ws, size_t ws_size,
                              hipStream_t stream) {
  const float* occ  = (const float*)d_in[0];
  const float* prc  = (const float*)d_in[1];
  const int*   ei   = (const int*)d_in[2];
  const float* W1   = (const float*)d_in[3];
  const float* as1  = (const float*)d_in[4];
  const float* ad1  = (const float*)d_in[5];
  const float* b1   = (const float*)d_in[6];
  const float* W2   = (const float*)d_in[7];
  const float* as2  = (const float*)d_in[8];
  const float* ad2  = (const float*)d_in[9];
  const float* b2   = (const float*)d_in[10];
  const float* decW = (const float*)d_in[11];
  const float* decb = (const float*)d_in[12];
  int E = in_sizes[2] / 2;

  float* ws = (float*)d_ws;
  float* xf   = ws;                       // NROWS * XPAD * 2
  float* h1s  = xf + (size_t)NROWS * XPAD * 2;  // 1024*32
  float* a1s  = h1s + NSMALL * PADH;      // 1024*4
  float* a1d  = a1s + NSMALL * 4;         // 1024*4
  float* h2s  = a1d + NSMALL * 4;         // 1024
  float* a2s  = h2s + NSMALL;             // 1024
  float* a2d  = a2s + NSMALL;             // 1024
  float* vsm  = a2d + NSMALL;             // 1024
  int*   cnt  = (int*)(vsm + NSMALL);     // 1024
  int*   srcs2 = cnt + NSMALL;            // 1024*CAP

  // node 1: double-folded recurrence transform (block 0 zeroes cnt)
  k_xf<<<NROWS / 2, 256, 0, stream>>>(occ, prc, xf, cnt);

  // node 2: cooperative {post+scatter -> g1 -> g2}; fallback = 3 kernels
  float* outp = (float*)d_out;
  void* args[] = {
    (void*)&xf, (void*)&W1, (void*)&b1, (void*)&W2, (void*)&b2,
    (void*)&as1, (void*)&ad1, (void*)&as2, (void*)&ad2,
    (void*)&decW, (void*)&decb, (void*)&ei, (void*)&E,
    (void*)&outp, (void*)&vsm, (void*)&h1s, (void*)&a1s, (void*)&a1d,
    (void*)&h2s, (void*)&a2s, (void*)&a2d, (void*)&cnt, (void*)&srcs2
  };
  hipError_t err = hipLaunchCooperativeKernel(
      reinterpret_cast<void*>(k_coop), dim3(512), dim3(256), args, 0, stream);
  if (err != hipSuccess) {
    k_post<<<NROWS + 32, 256, 0, stream>>>(xf, W1, b1, W2, b2, as1, ad1,
                                           decW, decb, outp, vsm,
                                           h1s, a1s, a1d, ei, E, cnt, srcs2);
    k_g1<<<NSMALL / 4, 256, 0, stream>>>(cnt, srcs2, a1s, a1d, h1s,
                                         b1, W2, as2, ad2, h2s, a2s, a2d);
    k_g2<<<NSMALL / 4, 256, 0, stream>>>(cnt, srcs2, a2s, a2d, h2s, b2,
                                         vsm, decW, outp);
  }
}

// Round 20
// 54.154 us; speedup vs baseline: 3.4071x; 3.4071x over previous
//
#include <hip/hip_runtime.h>
#include <math.h>

// ---- problem constants (fixed by reference setup) ----
constexpr int Bc    = 4;
constexpr int Nc    = 1024;
constexpr int SEQc  = 512;
constexpr int FOURc = 257;              // rfft output length
constexpr int NROWS = Bc * Nc;          // 4096 (b,n) rows
constexpr int NSMALL = 1024;            // nodes touched by real edges
constexpr int F1c   = 30;               // H1*C1
constexpr int PADH  = 32;               // h1s padded stride (float4-aligned)
constexpr int CAP   = 128;              // max in-degree bucket capacity
constexpr int XPAD  = 258;              // xf row stride (pad for 16B alignment)
constexpr float NEG_SLOPE = 0.2f;

#define DEVFN static __device__ __forceinline__

// ------- K_xf: double-folded Chebyshev cos-transform -> xf buffer -----------
// (r14-proven; r15/r19 lessons: do NOT fuse heavy epilogues or go cooperative.)
__global__ __launch_bounds__(256) void k_xf(
    const float* __restrict__ occ, const float* __restrict__ prc,
    float* __restrict__ xf, int* __restrict__ cnt) {
  __shared__ float4 z[2][128];            // [row][t]: zp_o, zp_p, zm_o, zm_p
  __shared__ float sp[2][6];              // y0_o,y0_p, y128_o,y128_p, x256_o,x256_p
  const int tid  = threadIdx.x;
  const int lane = tid & 63;
  const int wid  = tid >> 6;
  const int jrow = wid >> 1;              // local row 0..1
  const int half = wid & 1;               // column half 0..1
  const int row  = blockIdx.x * 2 + jrow;

  if (blockIdx.x == 0) {                  // zero bucket counters for the scatter
#pragma unroll
    for (int j = 0; j < 4; ++j) cnt[tid + 256 * j] = 0;
  }

  // staging: tid -> (row j = tid>>7, t = tid&127)
  {
    const int j = tid >> 7;
    const int t = tid & 127;
    const float* ro = occ + (size_t)(blockIdx.x * 2 + j) * SEQc;
    const float* rp = prc + (size_t)(blockIdx.x * 2 + j) * SEQc;
    if (t == 0) {
      sp[j][0] = ro[0];                 sp[j][1] = rp[0];
      sp[j][2] = ro[128] + ro[384];     sp[j][3] = rp[128] + rp[384];
      sp[j][4] = ro[256];               sp[j][5] = rp[256];
    } else {
      float ao = ro[t] + ro[SEQc - t];          // y[t]
      float bo = ro[256 - t] + ro[256 + t];     // y[256-t]
      float ap = rp[t] + rp[SEQc - t];
      float bp = rp[256 - t] + rp[256 + t];
      z[j][t] = make_float4(ao + bo, ap + bp, ao - bo, ap - bp);
    }
  }
  __syncthreads();

  // seeds for cols k0 (even), k0+1 (odd)
  const int k0 = half * 128 + 2 * lane;
  const float a = 6.283185307179586f / 512.0f;  // = pi/256
  float ce = cosf((float)k0 * a),       cpe = 1.f, m2e = 2.f * ce;
  float co = cosf((float)(k0 + 1) * a), cpo = 1.f, m2o = 2.f * co;
  float aeo = 0.f, aep = 0.f, aoo = 0.f, aop = 0.f;

#pragma unroll 4
  for (int t = 1; t < 128; ++t) {
    float4 zv = z[jrow][t];
    aeo = fmaf(zv.x, ce, aeo);
    aep = fmaf(zv.y, ce, aep);
    aoo = fmaf(zv.z, co, aoo);
    aop = fmaf(zv.w, co, aop);
    float ne = fmaf(m2e, ce, -cpe); cpe = ce; ce = ne;
    float no = fmaf(m2o, co, -cpo); cpo = co; co = no;
  }

  const float y0o = sp[jrow][0], y0p = sp[jrow][1];
  const float y128o = sp[jrow][2], y128p = sp[jrow][3];
  const float x256o = sp[jrow][4], x256p = sp[jrow][5];
  const float s128 = (lane & 1) ? -1.f : 1.f;   // (-1)^(k0/2)

  float4 st;                              // {Xe_o, Xe_p, Xo_o, Xo_p}
  st.x = aeo + y0o + s128 * y128o + x256o;
  st.y = aep + y0p + s128 * y128p + x256p;
  st.z = aoo + y0o - x256o;
  st.w = aop + y0p - x256p;
  *reinterpret_cast<float4*>(xf + ((size_t)row * XPAD + k0) * 2) = st;

  // k = 256 column: X256 = y0 + y128 + sum_{t=1}^{127} (-1)^t zp[t] + x256
  if (half == 0) {
    float sgn = (lane & 1) ? -1.f : 1.f;
    float4 zhi = z[jrow][lane + 64];
    float so = sgn * zhi.x, spp = sgn * zhi.y;
    if (lane >= 1) {
      float4 zlo = z[jrow][lane];
      so  = fmaf(sgn, zlo.x, so);
      spp = fmaf(sgn, zlo.y, spp);
    }
#pragma unroll
    for (int off = 32; off; off >>= 1) {
      so  += __shfl_xor(so, off);
      spp += __shfl_xor(spp, off);
    }
    if (lane == 0) {
      float2 st2;
      st2.x = y0o + y128o + so + x256o;
      st2.y = y0p + y128p + spp + x256p;
      *reinterpret_cast<float2*>(xf + ((size_t)row * XPAD + 256) * 2) = st2;
    }
  }
}

// self-loop-only node value: v = elu(xf@W1 + b1) @ W2 + b2
DEVFN float node_v(float xo, float xp,
                   const float* w1s, const float* b1s, const float* w2s, float b2v) {
  float s = 0.f;
#pragma unroll
  for (int jj = 0; jj < F1c; ++jj) {
    float h = fmaf(xo, w1s[jj], fmaf(xp, w1s[F1c + jj], b1s[jj]));
    float e = h > 0.f ? h : (__expf(h) - 1.f);
    s = fmaf(e, w2s[jj], s);
  }
  return s + b2v;
}

// layer-1 prep for small-graph nodes (padded strides: h1s 32, a1s/a1d 4)
DEVFN void small_prep(int node, float xo, float xp,
                      const float* w1s, const float* s1, const float* d1,
                      float* h1s, float* a1s, float* a1d) {
#pragma unroll
  for (int h = 0; h < 3; ++h) {
    float as = 0.f, ad = 0.f;
#pragma unroll
    for (int c = 0; c < 10; ++c) {
      int jj = h * 10 + c;
      float hv = fmaf(xo, w1s[jj], xp * w1s[F1c + jj]);
      h1s[node * PADH + jj] = hv;
      as = fmaf(hv, s1[jj], as);
      ad = fmaf(hv, d1[jj], ad);
    }
    a1s[node * 4 + h] = as;
    a1d[node * 4 + h] = ad;
  }
}

// ------- K_post: node_v + fused decode + small-graph prep ------------------
//          + bucket scatter in extra blocks (merged k_pre).
__global__ __launch_bounds__(256) void k_post(
    const float* __restrict__ xf,
    const float* __restrict__ W1, const float* __restrict__ b1,
    const float* __restrict__ W2, const float* __restrict__ b2,
    const float* __restrict__ as1, const float* __restrict__ ad1,
    const float* __restrict__ decW, const float* __restrict__ decb,
    float* __restrict__ out, float* __restrict__ vsm,
    float* __restrict__ h1s, float* __restrict__ a1s, float* __restrict__ a1d,
    const int* __restrict__ ei, int E,
    int* __restrict__ cnt, int* __restrict__ srcs2) {
  const int tid = threadIdx.x;

  if (blockIdx.x >= NROWS) {              // ---- bucket scatter blocks ----
    const int base = (blockIdx.x - NROWS) * 256 + tid;
    const int tot  = E + NSMALL;
    for (int e = base; e < tot; e += 32 * 256) {
      int src, dst;
      if (e < E) { src = ei[e]; dst = ei[E + e]; }
      else       { src = dst = e - E; }   // self loops
      int pos = atomicAdd(&cnt[dst], 1);
      if (pos < CAP) srcs2[dst * CAP + pos] = src;
    }
    return;
  }

  __shared__ float wl[192];               // W1(60) b1(30) W2(30) as1(30) ad1(30)
  __shared__ float red[4];
  const int row = blockIdx.x;
  if      (tid < 60)  wl[tid] = W1[tid];
  else if (tid < 90)  wl[tid] = b1[tid - 60];
  else if (tid < 120) wl[tid] = W2[tid - 90];
  else if (tid < 150) wl[tid] = as1[tid - 120];
  else if (tid < 180) wl[tid] = ad1[tid - 150];
  __syncthreads();
  const float* w1s = wl;
  const float* b1s = wl + 60;
  const float* w2s = wl + 90;
  const float* s1  = wl + 120;
  const float* d1  = wl + 150;
  const float b2v  = b2[0];
  const bool smallrow = (row < 4);

  float2 v2 = *reinterpret_cast<const float2*>(xf + ((size_t)row * XPAD + tid) * 2);
  float vv = node_v(v2.x, v2.y, w1s, b1s, w2s, b2v);
  float s = vv * decW[tid];
  if (tid == 0) {                         // col 256
    float2 v6 = *reinterpret_cast<const float2*>(xf + ((size_t)row * XPAD + 256) * 2);
    float v256 = node_v(v6.x, v6.y, w1s, b1s, w2s, b2v);
    s = fmaf(v256, decW[256], s);
    if (smallrow) {
      int node = row * FOURc + 256;
      if (node < NSMALL) {
        vsm[node] = v256;
        small_prep(node, v6.x, v6.y, w1s, s1, d1, h1s, a1s, a1d);
      }
    }
  }
  if (smallrow) {
    int node = row * FOURc + tid;
    if (node < NSMALL) {
      vsm[node] = vv;
      small_prep(node, v2.x, v2.y, w1s, s1, d1, h1s, a1s, a1d);
    }
  }
#pragma unroll
  for (int off = 32; off; off >>= 1) s += __shfl_xor(s, off);
  if ((tid & 63) == 0) red[tid >> 6] = s;
  __syncthreads();
  if (tid == 0) out[row] = red[0] + red[1] + red[2] + red[3] + decb[0];
}

// ------- K_g1: layer-1 gather (one wave per dst), vectorized h1s loads -----
__global__ __launch_bounds__(256) void k_g1(
    const int* __restrict__ cnt, const int* __restrict__ srcs2,
    const float* __restrict__ a1s, const float* __restrict__ a1d,
    const float* __restrict__ h1s,
    const float* __restrict__ b1, const float* __restrict__ W2,
    const float* __restrict__ as2, const float* __restrict__ ad2,
    float* __restrict__ h2s, float* __restrict__ a2s, float* __restrict__ a2d) {
  const int lane = threadIdx.x & 63;
  const int dst  = blockIdx.x * 4 + (threadIdx.x >> 6);
  const int deg  = cnt[dst];
  const int* sp  = srcs2 + dst * CAP;
  const float ad0 = a1d[dst * 4], ad1v = a1d[dst * 4 + 1], ad2v = a1d[dst * 4 + 2];
  float den[3] = {0.f, 0.f, 0.f};
  float num[F1c];
#pragma unroll
  for (int j = 0; j < F1c; ++j) num[j] = 0.f;

  for (int p = lane; p < deg; p += 64) {
    int src = sp[p];
    const float4* hs4 = reinterpret_cast<const float4*>(h1s + src * PADH);
    float4 av = *reinterpret_cast<const float4*>(a1s + src * 4);
    float x0 = av.x + ad0;
    float x1 = av.y + ad1v;
    float x2 = av.z + ad2v;
    x0 = x0 > 0.f ? x0 : NEG_SLOPE * x0;
    x1 = x1 > 0.f ? x1 : NEG_SLOPE * x1;
    x2 = x2 > 0.f ? x2 : NEG_SLOPE * x2;
    float ev[3] = {__expf(x0), __expf(x1), __expf(x2)};
    den[0] += ev[0]; den[1] += ev[1]; den[2] += ev[2];
#pragma unroll
    for (int m = 0; m < 7; ++m) {
      float4 hv = hs4[m];
      num[4 * m + 0] = fmaf(ev[(4 * m + 0) / 10], hv.x, num[4 * m + 0]);
      num[4 * m + 1] = fmaf(ev[(4 * m + 1) / 10], hv.y, num[4 * m + 1]);
      num[4 * m + 2] = fmaf(ev[(4 * m + 2) / 10], hv.z, num[4 * m + 2]);
      num[4 * m + 3] = fmaf(ev[(4 * m + 3) / 10], hv.w, num[4 * m + 3]);
    }
    float2 h7 = *reinterpret_cast<const float2*>(h1s + src * PADH + 28);
    num[28] = fmaf(ev[2], h7.x, num[28]);
    num[29] = fmaf(ev[2], h7.y, num[29]);
  }
#pragma unroll
  for (int h = 0; h < 3; ++h)
#pragma unroll
    for (int off = 32; off; off >>= 1) den[h] += __shfl_xor(den[h], off);
#pragma unroll
  for (int j = 0; j < F1c; ++j)
#pragma unroll
    for (int off = 32; off; off >>= 1) num[j] += __shfl_xor(num[j], off);

  if (lane == 0) {
    float h2 = 0.f;
#pragma unroll
    for (int jj = 0; jj < F1c; ++jj) {
      float x2 = num[jj] / den[jj / 10] + b1[jj];
      x2 = x2 > 0.f ? x2 : (__expf(x2) - 1.f);
      h2 = fmaf(x2, W2[jj], h2);
    }
    h2s[dst] = h2;
    a2s[dst] = h2 * as2[0];
    a2d[dst] = h2 * ad2[0];
  }
}

// ------- K_g2: layer-2 gather + fused row-decode correction -------
__global__ __launch_bounds__(256) void k_g2(
    const int* __restrict__ cnt, const int* __restrict__ srcs2,
    const float* __restrict__ a2s, const float* __restrict__ a2d,
    const float* __restrict__ h2s, const float* __restrict__ b2,
    const float* __restrict__ vsm, const float* __restrict__ decW,
    float* __restrict__ out) {
  __shared__ float rcor[4];
  __shared__ int   rrow[4];
  const int tid  = threadIdx.x;
  const int lane = tid & 63;
  const int wid  = tid >> 6;
  const int dst  = blockIdx.x * 4 + wid;
  const int deg  = cnt[dst];
  const int* sp  = srcs2 + dst * CAP;
  const float adv = a2d[dst];
  float den = 0.f, num = 0.f;
  for (int p = lane; p < deg; p += 64) {
    int src = sp[p];
    float x = a2s[src] + adv;
    x = x > 0.f ? x : NEG_SLOPE * x;
    float ex = __expf(x);
    den += ex;
    num = fmaf(ex, h2s[src], num);
  }
#pragma unroll
  for (int off = 32; off; off >>= 1) {
    den += __shfl_xor(den, off);
    num += __shfl_xor(num, off);
  }
  if (lane == 0) {
    float val2v = num / den + b2[0];
    int r = dst / FOURc;
    int k = dst - r * FOURc;
    rcor[wid] = (val2v - vsm[dst]) * decW[k];
    rrow[wid] = r;
  }
  __syncthreads();
  if (tid == 0) {
    float acc = rcor[0];
#pragma unroll
    for (int i = 1; i < 4; ++i) {
      if (rrow[i] == rrow[0]) acc += rcor[i];
      else atomicAdd(&out[rrow[i]], rcor[i]);
    }
    atomicAdd(&out[rrow[0]], acc);
  }
}

// ---------------- host launcher ----------------
extern "C" void kernel_launch(void* const* d_in, const int* in_sizes, int n_in,
                              void* d_out, int out_size, void* d_ws, size_t ws_size,
                              hipStream_t stream) {
  const float* occ  = (const float*)d_in[0];
  const float* prc  = (const float*)d_in[1];
  const int*   ei   = (const int*)d_in[2];
  const float* W1   = (const float*)d_in[3];
  const float* as1  = (const float*)d_in[4];
  const float* ad1  = (const float*)d_in[5];
  const float* b1   = (const float*)d_in[6];
  const float* W2   = (const float*)d_in[7];
  const float* as2  = (const float*)d_in[8];
  const float* ad2  = (const float*)d_in[9];
  const float* b2   = (const float*)d_in[10];
  const float* decW = (const float*)d_in[11];
  const float* decb = (const float*)d_in[12];
  const int E = in_sizes[2] / 2;

  float* ws = (float*)d_ws;
  float* xf   = ws;                       // NROWS * XPAD * 2
  float* h1s  = xf + (size_t)NROWS * XPAD * 2;  // 1024*32
  float* a1s  = h1s + NSMALL * PADH;      // 1024*4
  float* a1d  = a1s + NSMALL * 4;         // 1024*4
  float* h2s  = a1d + NSMALL * 4;         // 1024
  float* a2s  = h2s + NSMALL;             // 1024
  float* a2d  = a2s + NSMALL;             // 1024
  float* vsm  = a2d + NSMALL;             // 1024
  int*   cnt  = (int*)(vsm + NSMALL);     // 1024
  int*   srcs2 = cnt + NSMALL;            // 1024*CAP

  // node 1: double-folded recurrence transform (block 0 zeroes cnt)
  k_xf<<<NROWS / 2, 256, 0, stream>>>(occ, prc, xf, cnt);

  // node 2: node_v + decode + small-graph prep, PLUS bucket scatter blocks
  k_post<<<NROWS + 32, 256, 0, stream>>>(xf, W1, b1, W2, b2, as1, ad1,
                                         decW, decb, (float*)d_out, vsm,
                                         h1s, a1s, a1d, ei, E, cnt, srcs2);

  // node 3: layer-1 gather
  k_g1<<<NSMALL / 4, 256, 0, stream>>>(cnt, srcs2, a1s, a1d, h1s,
                                       b1, W2, as2, ad2, h2s, a2s, a2d);
  // node 4: layer-2 gather + fused decode correction for rows 0..3
  k_g2<<<NSMALL / 4, 256, 0, stream>>>(cnt, srcs2, a2s, a2d, h2s, b2,
                                       vsm, decW, (float*)d_out);
}